// Round 2
// baseline (124.258 us; speedup 1.0000x reference)
//
#include <hip/hip_runtime.h>

#define B_ 64
#define K_ 16
#define N_ 65536
#define CHUNKS 16
#define NPAIR 120            // pairs (k,l) with k<l
#define NVAL 136             // 120 pair sums + 16 rowsums
#define PPW 30               // pairs per wave (120 / 4 waves)
#define RPW 4                // rowsums per wave (16 / 4 waves)
#define EPS_ 1e-8f
#define SMOOTH_ 0.1f

// Compile-time pair table: pair p -> (k,l), k<l.
struct PairTab {
    int pk[NPAIR];
    int pl[NPAIR];
    constexpr PairTab() : pk(), pl() {
        int p = 0;
        for (int a = 0; a < K_; ++a)
            for (int b = a + 1; b < K_; ++b) { pk[p] = a; pl[p] = b; ++p; }
    }
};
constexpr PairTab PT{};

// ---- DPP wave-64 sum: result lands in lane 63 (VALU pipe, no LDS) ----
template <int CTRL>
__device__ __forceinline__ float dpp_add_step(float x) {
    int y = __builtin_amdgcn_update_dpp(0, __float_as_int(x), CTRL, 0xf, 0xf, true);
    return x + __int_as_float(y);
}

__device__ __forceinline__ float wave_sum_lane63(float x) {
    x = dpp_add_step<0x111>(x); // row_shr:1
    x = dpp_add_step<0x112>(x); // row_shr:2
    x = dpp_add_step<0x114>(x); // row_shr:4
    x = dpp_add_step<0x118>(x); // row_shr:8  -> lane 15 of each row16 = row sum
    x = dpp_add_step<0x142>(x); // row_bcast:15
    x = dpp_add_step<0x143>(x); // row_bcast:31 -> lane 63 = full wave sum
    return x;
}

__global__ void zero_ws(float* __restrict__ ws) {
    int i = blockIdx.x * 256 + threadIdx.x;
    if (i < B_ * NVAL) ws[i] = 0.f;
}

// Each wave of a block owns 30 pairs + 4 rowsums; all 4 waves scan the same
// column range (loads dedup in L1/L2). Per-thread live regs ~105 -> no spill.
template <int W>
__device__ __forceinline__ void wave_body(const float4* __restrict__ base,
                                          int lane, int chunk,
                                          float* __restrict__ wsb) {
    float g[PPW];
    float rs[RPW];
#pragma unroll
    for (int i = 0; i < PPW; ++i) g[i] = 0.f;
#pragma unroll
    for (int r = 0; r < RPW; ++r) rs[r] = 0.f;

    int idx = chunk * (N_ / CHUNKS / 4) + lane;   // float4 index within a row

#pragma unroll 1
    for (int it = 0; it < (N_ / CHUNKS) / (4 * 64); ++it) {  // 16 iterations
        float4 v[K_];
#pragma unroll
        for (int k = 0; k < K_; ++k) v[k] = base[k * (N_ / 4) + idx];
#pragma unroll
        for (int r = 0; r < RPW; ++r) {
            const float4 x = v[W * RPW + r];
            rs[r] += (x.x + x.y) + (x.z + x.w);
        }
#pragma unroll
        for (int i = 0; i < PPW; ++i) {
            const int k = PT.pk[W * PPW + i];     // compile-time after unroll
            const int l = PT.pl[W * PPW + i];
            g[i] += v[k].x * v[l].x + v[k].y * v[l].y
                  + v[k].z * v[l].z + v[k].w * v[l].w;
        }
        idx += 64;
    }

#pragma unroll
    for (int i = 0; i < PPW; ++i) {
        float s = wave_sum_lane63(g[i]);
        if (lane == 63) atomicAdd(&wsb[W * PPW + i], s);
    }
#pragma unroll
    for (int r = 0; r < RPW; ++r) {
        float s = wave_sum_lane63(rs[r]);
        if (lane == 63) atomicAdd(&wsb[NPAIR + W * RPW + r], s);
    }
}

__global__ __launch_bounds__(256, 4)
void dice_accum(const float* __restrict__ am, float* __restrict__ ws) {
    const int b     = blockIdx.x >> 4;            // CHUNKS == 16
    const int chunk = blockIdx.x & (CHUNKS - 1);
    const int tid   = threadIdx.x;
    const int lane  = tid & 63;
    const int w     = tid >> 6;

    const float4* __restrict__ base =
        reinterpret_cast<const float4*>(am) + (size_t)b * K_ * (N_ / 4);
    float* __restrict__ wsb = ws + b * NVAL;

    if      (w == 0) wave_body<0>(base, lane, chunk, wsb);
    else if (w == 1) wave_body<1>(base, lane, chunk, wsb);
    else if (w == 2) wave_body<2>(base, lane, chunk, wsb);
    else             wave_body<3>(base, lane, chunk, wsb);
}

// Deferred normalization + dice + mean over (b, pairs). Tiny.
__global__ void dice_finalize(const float* __restrict__ ws, float* __restrict__ out) {
    const int tid = threadIdx.x;
    __shared__ float red[128];
    float acc = 0.f;
    if (tid < NPAIR) {
        int rem = tid, k = 0;
        while (rem >= K_ - 1 - k) { rem -= K_ - 1 - k; ++k; }
        const int l = k + 1 + rem;
        for (int b = 0; b < B_; ++b) {
            const float* wsb = ws + b * NVAL;
            float rsk  = wsb[NPAIR + k];
            float rsl  = wsb[NPAIR + l];
            float graw = wsb[tid];
            float dk = rsk + EPS_, dl = rsl + EPS_;
            float gram = graw / (dk * dl);          // gram of normalized an
            float u    = rsk / dk + rsl / dl;       // sums_k + sums_l
            acc += (2.f * gram + SMOOTH_) / (u + SMOOTH_);
        }
    }
    red[tid] = acc;
    __syncthreads();
    if (tid == 0) {
        float t = 0.f;
        for (int i = 0; i < 128; ++i) t += red[i];
        out[0] = t / (float)(B_ * NPAIR);
    }
}

extern "C" void kernel_launch(void* const* d_in, const int* in_sizes, int n_in,
                              void* d_out, int out_size, void* d_ws, size_t ws_size,
                              hipStream_t stream) {
    const float* am = (const float*)d_in[0];
    float* ws  = (float*)d_ws;
    float* out = (float*)d_out;

    hipLaunchKernelGGL(zero_ws, dim3((B_ * NVAL + 255) / 256), dim3(256), 0, stream, ws);
    hipLaunchKernelGGL(dice_accum, dim3(B_ * CHUNKS), dim3(256), 0, stream, am, ws);
    hipLaunchKernelGGL(dice_finalize, dim3(1), dim3(128), 0, stream, ws, out);
}

// Round 3
// 100.808 us; speedup vs baseline: 1.2326x; 1.2326x over previous
//
#include <hip/hip_runtime.h>

#define B_ 64
#define K_ 16
#define N_ 65536
#define CHUNKS 16
#define ITERS ((N_ / CHUNKS) / (4 * 64))   // 16 iterations of 1KB-per-row
#define NPAIR 120            // pairs (k,l) with k<l
#define NVAL 136             // 120 pair sums + 16 rowsums
#define PPW 30               // pairs per wave (120 / 4 waves)
#define RPW 4                // rowsums per wave (16 / 4 waves)
#define EPS_ 1e-8f
#define SMOOTH_ 0.1f

// Compile-time pair table: pair p -> (k,l), k<l.
struct PairTab {
    int pk[NPAIR];
    int pl[NPAIR];
    constexpr PairTab() : pk(), pl() {
        int p = 0;
        for (int a = 0; a < K_; ++a)
            for (int b = a + 1; b < K_; ++b) { pk[p] = a; pl[p] = b; ++p; }
    }
};
constexpr PairTab PT{};

// ---- DPP wave-64 sum: result lands in lane 63 (VALU pipe, no LDS) ----
template <int CTRL>
__device__ __forceinline__ float dpp_add_step(float x) {
    int y = __builtin_amdgcn_update_dpp(0, __float_as_int(x), CTRL, 0xf, 0xf, true);
    return x + __int_as_float(y);
}

__device__ __forceinline__ float wave_sum_lane63(float x) {
    x = dpp_add_step<0x111>(x); // row_shr:1
    x = dpp_add_step<0x112>(x); // row_shr:2
    x = dpp_add_step<0x114>(x); // row_shr:4
    x = dpp_add_step<0x118>(x); // row_shr:8  -> lane 15 of each row16 = row sum
    x = dpp_add_step<0x142>(x); // row_bcast:15
    x = dpp_add_step<0x143>(x); // row_bcast:31 -> lane 63 = full wave sum
    return x;
}

__global__ void zero_ws(float* __restrict__ ws) {
    int i = blockIdx.x * 256 + threadIdx.x;
    if (i < B_ * NVAL) ws[i] = 0.f;
}

// Each wave of a block owns 30 pairs + 4 rowsums; all 4 waves scan the same
// column range (loads dedup in L1/L2). Per-block phase rotation `rot`
// de-aliases the 32KB channel-interleave period across co-resident blocks.
template <int W>
__device__ __forceinline__ void wave_body(const float4* __restrict__ base,
                                          int lane, int chunk, int rot,
                                          float* __restrict__ wsb) {
    float g[PPW];
    float rs[RPW];
#pragma unroll
    for (int i = 0; i < PPW; ++i) g[i] = 0.f;
#pragma unroll
    for (int r = 0; r < RPW; ++r) rs[r] = 0.f;

    const int idxBase = chunk * (N_ / CHUNKS / 4);

#pragma unroll 1
    for (int s = 0; s < ITERS; ++s) {
        const int it  = (s + rot) & (ITERS - 1);   // rotated phase within chunk
        const int idx = idxBase + it * 64 + lane;
        float4 v[K_];
#pragma unroll
        for (int k = 0; k < K_; ++k) v[k] = base[k * (N_ / 4) + idx];
#pragma unroll
        for (int r = 0; r < RPW; ++r) {
            const float4 x = v[W * RPW + r];
            rs[r] += (x.x + x.y) + (x.z + x.w);
        }
#pragma unroll
        for (int i = 0; i < PPW; ++i) {
            const int k = PT.pk[W * PPW + i];     // compile-time after unroll
            const int l = PT.pl[W * PPW + i];
            g[i] += v[k].x * v[l].x + v[k].y * v[l].y
                  + v[k].z * v[l].z + v[k].w * v[l].w;
        }
    }

#pragma unroll
    for (int i = 0; i < PPW; ++i) {
        float s = wave_sum_lane63(g[i]);
        if (lane == 63) atomicAdd(&wsb[W * PPW + i], s);
    }
#pragma unroll
    for (int r = 0; r < RPW; ++r) {
        float s = wave_sum_lane63(rs[r]);
        if (lane == 63) atomicAdd(&wsb[NPAIR + W * RPW + r], s);
    }
}

__global__ __launch_bounds__(256, 4)
void dice_accum(const float* __restrict__ am, float* __restrict__ ws) {
    const int b     = blockIdx.x >> 4;            // CHUNKS == 16
    const int chunk = blockIdx.x & (CHUNKS - 1);
    const int tid   = threadIdx.x;
    const int lane  = tid & 63;
    const int w     = tid >> 6;
    const int rot   = (b + chunk) & (ITERS - 1);  // phase de-aliasing

    const float4* __restrict__ base =
        reinterpret_cast<const float4*>(am) + (size_t)b * K_ * (N_ / 4);
    float* __restrict__ wsb = ws + b * NVAL;

    if      (w == 0) wave_body<0>(base, lane, chunk, rot, wsb);
    else if (w == 1) wave_body<1>(base, lane, chunk, rot, wsb);
    else if (w == 2) wave_body<2>(base, lane, chunk, rot, wsb);
    else             wave_body<3>(base, lane, chunk, rot, wsb);
}

// Deferred normalization + dice + mean. 960 threads: pair p x 8 batch-groups.
__global__ __launch_bounds__(960)
void dice_finalize(const float* __restrict__ ws, float* __restrict__ out) {
    const int tid = threadIdx.x;
    __shared__ float red[960];
    const int p  = tid % NPAIR;
    const int bg = tid / NPAIR;       // 0..7
    int rem = p, k = 0;
    while (rem >= K_ - 1 - k) { rem -= K_ - 1 - k; ++k; }
    const int l = k + 1 + rem;
    float acc = 0.f;
#pragma unroll
    for (int j = 0; j < B_ / 8; ++j) {
        const int b = bg * (B_ / 8) + j;
        const float* wsb = ws + b * NVAL;
        float rsk  = wsb[NPAIR + k];
        float rsl  = wsb[NPAIR + l];
        float graw = wsb[p];
        float dk = rsk + EPS_, dl = rsl + EPS_;
        float gram = graw / (dk * dl);          // gram of normalized an
        float u    = rsk / dk + rsl / dl;       // sums_k + sums_l
        acc += (2.f * gram + SMOOTH_) / (u + SMOOTH_);
    }
    red[tid] = acc;
    __syncthreads();
    // fold 960 -> 120 (threads 0..119 each sum their 8 bg copies)
    if (tid < NPAIR) {
        float t = 0.f;
#pragma unroll
        for (int j = 0; j < 8; ++j) t += red[j * NPAIR + tid];
        red[tid] = t;
    }
    __syncthreads();
    // wave 0 reduces 120 values: lane reads [lane] and [lane+64]
    if (tid < 64) {
        float t = red[tid] + ((tid + 64 < NPAIR) ? red[tid + 64] : 0.f);
        t = wave_sum_lane63(t);
        if (tid == 63) out[0] = t / (float)(B_ * NPAIR);
    }
}

extern "C" void kernel_launch(void* const* d_in, const int* in_sizes, int n_in,
                              void* d_out, int out_size, void* d_ws, size_t ws_size,
                              hipStream_t stream) {
    const float* am = (const float*)d_in[0];
    float* ws  = (float*)d_ws;
    float* out = (float*)d_out;

    hipLaunchKernelGGL(zero_ws, dim3((B_ * NVAL + 255) / 256), dim3(256), 0, stream, ws);
    hipLaunchKernelGGL(dice_accum, dim3(B_ * CHUNKS), dim3(256), 0, stream, am, ws);
    hipLaunchKernelGGL(dice_finalize, dim3(1), dim3(960), 0, stream, ws, out);
}

// Round 4
// 55.983 us; speedup vs baseline: 2.2196x; 1.8007x over previous
//
#include <hip/hip_runtime.h>

#define B_ 64
#define K_ 16
#define N_ 65536
#define CHUNKS 16
#define CW (N_ / CHUNKS)          // 4096 columns per block
#define KB_PER_WAVE (CW / 32 / 4) // 32 kblocks of 32 cols per wave
#define U_ 4                      // kblocks in flight per wave
#define REC 320                   // 256 gram + 64 rowsum slots per wave record
#define NPAIR 120
#define EPS_ 1e-8f
#define SMOOTH_ 0.1f

typedef __attribute__((ext_vector_type(8))) short bf16x8;
typedef __attribute__((ext_vector_type(4))) float f32x4;

// RNE f32 -> bf16 bit pattern (data is finite positive; no NaN path needed)
__device__ __forceinline__ short f2bf(float f) {
    unsigned u = __float_as_uint(f);
    return (short)((u + 0x7FFFu + ((u >> 16) & 1u)) >> 16);
}

// ---- DPP wave-64 sum: result lands in lane 63 ----
template <int CTRL>
__device__ __forceinline__ float dpp_add_step(float x) {
    int y = __builtin_amdgcn_update_dpp(0, __float_as_int(x), CTRL, 0xf, 0xf, true);
    return x + __int_as_float(y);
}
__device__ __forceinline__ float wave_sum_lane63(float x) {
    x = dpp_add_step<0x111>(x);
    x = dpp_add_step<0x112>(x);
    x = dpp_add_step<0x114>(x);
    x = dpp_add_step<0x118>(x);
    x = dpp_add_step<0x142>(x);
    x = dpp_add_step<0x143>(x);
    return x;
}

// Main pass: Gram via MFMA. Each lane loads 8 consecutive f32 of row (lane&15)
// at k-offset (lane>>4)*8 within a 32-col kblock -> bf16x8 frag; mfma(frag,frag)
// accumulates the 16x16 A.A^T tile. Rowsums taken from the f32 values.
__global__ __launch_bounds__(256, 4)
void dice_accum(const float* __restrict__ am, float* __restrict__ ws) {
    const int b     = blockIdx.x >> 4;           // CHUNKS == 16
    const int chunk = blockIdx.x & (CHUNKS - 1);
    const int tid   = threadIdx.x;
    const int lane  = tid & 63;
    const int w     = tid >> 6;
    const int row   = lane & 15;
    const int lg    = lane >> 4;                 // 0..3 k-group

    const float4* __restrict__ rp =
        reinterpret_cast<const float4*>(am)
        + (size_t)(b * K_ + row) * (N_ / 4)      // row base (float4 units)
        + chunk * (CW / 4)                       // chunk base
        + lg * 2;                                // k-group offset (8 f32)

    // phase rotation across the wave's 32 kblocks (channel de-aliasing)
    const int rot = (b + chunk * 5 + w * 8) & (KB_PER_WAVE - 1);

    f32x4 acc = {0.f, 0.f, 0.f, 0.f};
    float rs = 0.f;

#pragma unroll 1
    for (int i = 0; i < KB_PER_WAVE; i += U_) {
        float4 a[U_][2];
#pragma unroll
        for (int u = 0; u < U_; ++u) {
            const int kb = w + 4 * ((i + u + rot) & (KB_PER_WAVE - 1));
            a[u][0] = rp[kb * 8];
            a[u][1] = rp[kb * 8 + 1];
        }
#pragma unroll
        for (int u = 0; u < U_; ++u) {
            const float f0 = a[u][0].x, f1 = a[u][0].y, f2 = a[u][0].z, f3 = a[u][0].w;
            const float f4 = a[u][1].x, f5 = a[u][1].y, f6 = a[u][1].z, f7 = a[u][1].w;
            rs += ((f0 + f1) + (f2 + f3)) + ((f4 + f5) + (f6 + f7));
            bf16x8 frag;
            frag[0] = f2bf(f0); frag[1] = f2bf(f1);
            frag[2] = f2bf(f2); frag[3] = f2bf(f3);
            frag[4] = f2bf(f4); frag[5] = f2bf(f5);
            frag[6] = f2bf(f6); frag[7] = f2bf(f7);
            acc = __builtin_amdgcn_mfma_f32_16x16x32_bf16(frag, frag, acc, 0, 0, 0);
        }
    }

    // Write per-wave record: 256 gram (row*16+col; symmetric so transpose-safe)
    // + 64 raw lane rowsum partials (row = slot&15).
    float* __restrict__ rec = ws + ((size_t)blockIdx.x * 4 + w) * REC;
#pragma unroll
    for (int j = 0; j < 4; ++j) {
        const int rrow = lg * 4 + j;             // C/D layout: row=(lane>>4)*4+j
        rec[rrow * 16 + row] = acc[j];           // col = lane&15
    }
    rec[256 + lane] = rs;
}

// Per-b reduction over 64 wave-records + dice computation -> ws2[b]
__global__ __launch_bounds__(256)
void dice_finalize1(const float* __restrict__ ws, float* __restrict__ ws2) {
    const int b   = blockIdx.x;
    const int tid = threadIdx.x;
    __shared__ float G[256];
    __shared__ float RS[64];
    __shared__ float red[128];

    const float* __restrict__ base = ws + (size_t)b * CHUNKS * 4 * REC;

    float g = 0.f;
#pragma unroll 4
    for (int r = 0; r < CHUNKS * 4; ++r) g += base[r * REC + tid];
    G[tid] = g;

    if (tid < 64) {
        float s = 0.f;
#pragma unroll 4
        for (int r = 0; r < CHUNKS * 4; ++r) s += base[r * REC + 256 + tid];
        RS[tid] = s;
    }
    __syncthreads();
    if (tid < 16) RS[tid] = RS[tid] + RS[tid + 16] + RS[tid + 32] + RS[tid + 48];
    __syncthreads();

    float acc = 0.f;
    if (tid < NPAIR) {
        int rem = tid, k = 0;
        while (rem >= K_ - 1 - k) { rem -= K_ - 1 - k; ++k; }
        const int l = k + 1 + rem;
        const float rsk = RS[k], rsl = RS[l];
        const float dk = rsk + EPS_, dl = rsl + EPS_;
        const float gram = G[k * 16 + l] / (dk * dl);   // normalized gram
        const float u    = rsk / dk + rsl / dl;         // sums_k + sums_l
        acc = (2.f * gram + SMOOTH_) / (u + SMOOTH_);
    }
    if (tid < 128) red[tid] = acc;
    __syncthreads();
    if (tid < 64) {
        float t = red[tid] + red[tid + 64];
        t = wave_sum_lane63(t);
        if (tid == 63) ws2[b] = t;
    }
}

// Sum 64 per-b values -> final scalar
__global__ void dice_finalize2(const float* __restrict__ ws2, float* __restrict__ out) {
    float v = ws2[threadIdx.x];
    v = wave_sum_lane63(v);
    if (threadIdx.x == 63) out[0] = v / (float)(B_ * NPAIR);
}

extern "C" void kernel_launch(void* const* d_in, const int* in_sizes, int n_in,
                              void* d_out, int out_size, void* d_ws, size_t ws_size,
                              hipStream_t stream) {
    const float* am = (const float*)d_in[0];
    float* ws  = (float*)d_ws;
    float* ws2 = ws + (size_t)B_ * CHUNKS * 4 * REC;   // after 5.24 MB of records
    float* out = (float*)d_out;

    hipLaunchKernelGGL(dice_accum, dim3(B_ * CHUNKS), dim3(256), 0, stream, am, ws);
    hipLaunchKernelGGL(dice_finalize1, dim3(B_), dim3(256), 0, stream, ws, ws2);
    hipLaunchKernelGGL(dice_finalize2, dim3(1), dim3(64), 0, stream, ws2, out);
}